// Round 4
// baseline (2596.604 us; speedup 1.0000x reference)
//
#include <hip/hip_runtime.h>

// ---------------------------------------------------------------------------
// SortNet: 3-layer 1x1-conv MLP (64->64->16->1) with training-mode BatchNorm
// + ReLU, per-batch top-64 over N, gather of input + score.
//
// GEMM structure: thread owns 4 consecutive positions (float4 loads) x 16 (or
// 8) channels; weights are wave-uniform (scalar cache). Live set kept < 128
// VGPR (R3 lesson: exceeding it causes ~10x VALU rematerialization bloat).
//
// Pipeline (9 launches + 1 memset, deterministic):
//   k_prep      : transpose w0 (64x64) and w1 (16x64)
//   k_conv0stat : conv0 (4pos x 16ch/thread), per-channel sum/sumsq partials
//   k_reduce0   : finalize scale0/shift0
//   k_layer01   : recompute conv0 (4pos x 8ch), bn0+relu -> LDS h0[64][128],
//                 conv1 (4pos x 2out), y1 + stats1 partials
//   k_reduce1   : finalize scale1/shift1
//   k_layer2    : y2 = w2@relu(bn1(y1)) + b2, stats2 partials, per-batch
//                 4096-bin key histogram (radix-select pass 1)
//   k_thresh    : per batch, threshold bin T with count(bin >= T) >= 64
//   k_compact   : compact keys with bin >= T via atomics
//   k_final     : 1 wave/batch: 64 rounds of in-register wave argmax
//                 (jax tie-break), stats2 finalize, score decode, gather.
// ---------------------------------------------------------------------------

constexpr int   B_   = 16;
constexpr int   N_   = 32768;
constexpr int   K_   = 64;            // TOP_K
constexpr long long S_ = (long long)B_ * N_;   // 524288
constexpr float EPS_ = 1e-5f;

constexpr int NC0B = 512;     // k_conv0stat blocks (grid-stride)
constexpr int NC0T = 2048;    // conv0stat tiles (256 pos each)
constexpr int NL1B = 512;     // k_layer01 blocks (grid-stride)
constexpr int NL1T = 4096;    // layer01 tiles (128 pos each)
constexpr int NB2  = 256;     // k_layer2 blocks (2048 pos each)
constexpr int NBC  = 128;     // k_compact blocks (4096 pos each)
constexpr int NBINS = 4096;   // radix-select bins (key >> 20)
constexpr int CAP   = 1024;   // candidate capacity per batch

__device__ __forceinline__ unsigned key_map(float f) {
  unsigned u = __float_as_uint(f);
  return (u & 0x80000000u) ? ~u : (u | 0x80000000u);
}

// --------------------------- k_prep ----------------------------------------
__global__ __launch_bounds__(256) void k_prep(const float* __restrict__ w0,
                                              const float* __restrict__ w1,
                                              float* __restrict__ w0T,
                                              float* __restrict__ w1T) {
  int t = threadIdx.x;
  for (int e = t; e < 64 * 64; e += 256) {
    int o = e >> 6, f = e & 63;
    w0T[f * 64 + o] = w0[e];          // w0T[f][o] = w0[o][f]
  }
  for (int e = t; e < 16 * 64; e += 256) {
    int o = e >> 6, c = e & 63;
    w1T[c * 16 + o] = w1[e];          // w1T[c][o] = w1[o][c]
  }
}

// --------------------------- k_conv0stat -----------------------------------
// Tile = 256 positions. Thread (pg = t&63 -> 4 pos, cg = t>>6 -> 16 ch).
// Per f: one float4 load + 16 uniform weights + 64 FMA. No LDS, no barriers.
__global__ __launch_bounds__(256, 4) void k_conv0stat(const float* __restrict__ sv,
                                                      const float* __restrict__ w0T,
                                                      const float* __restrict__ b0,
                                                      float* __restrict__ p0) {
  const int t  = threadIdx.x;
  const int pg = t & 63;
  const int cg = t >> 6;              // == wave id, uniform

  float s1[16], s2[16];
#pragma unroll
  for (int j = 0; j < 16; ++j) { s1[j] = 0.f; s2[j] = 0.f; }

  for (int tile = blockIdx.x; tile < NC0T; tile += NC0B) {
    const int b  = tile >> 7;                      // 128 tiles per batch
    const int n0 = ((tile & 127) << 8) + (pg << 2);
    const float* xp = sv + ((long long)b * 64) * N_ + n0;

    float4 y[16];
#pragma unroll
    for (int j = 0; j < 16; ++j) {
      float bv = b0[cg * 16 + j];
      y[j].x = bv; y[j].y = bv; y[j].z = bv; y[j].w = bv;
    }
#pragma unroll
    for (int f = 0; f < 64; ++f) {
      const float4 x = *(const float4*)(xp + (long long)f * N_);
      const float* wr = w0T + f * 64 + cg * 16;    // wave-uniform
#pragma unroll
      for (int j = 0; j < 16; ++j) {
        const float w = wr[j];
        y[j].x = fmaf(w, x.x, y[j].x);
        y[j].y = fmaf(w, x.y, y[j].y);
        y[j].z = fmaf(w, x.z, y[j].z);
        y[j].w = fmaf(w, x.w, y[j].w);
      }
    }
#pragma unroll
    for (int j = 0; j < 16; ++j) {
      s1[j] += (y[j].x + y[j].y) + (y[j].z + y[j].w);
      s2[j] = fmaf(y[j].x, y[j].x,
              fmaf(y[j].y, y[j].y,
              fmaf(y[j].z, y[j].z,
              fmaf(y[j].w, y[j].w, s2[j]))));
    }
  }

#pragma unroll
  for (int j = 0; j < 16; ++j) {
#pragma unroll
    for (int off = 32; off; off >>= 1) {
      s1[j] += __shfl_down(s1[j], off, 64);
      s2[j] += __shfl_down(s2[j], off, 64);
    }
  }
  if (pg == 0) {
    float* dst = p0 + (long long)blockIdx.x * 128 + cg * 32;
#pragma unroll
    for (int j = 0; j < 16; ++j) { dst[j] = s1[j]; dst[16 + j] = s2[j]; }
  }
}

// --------------------------- k_reduce0 -------------------------------------
// p0 layout per block: [cg*32 + (0..15 s1 | 16..31 s2)], ch = cg*16 + j.
__global__ __launch_bounds__(128) void k_reduce0(const float* __restrict__ p0,
                                                 const float* __restrict__ g,
                                                 const float* __restrict__ bt,
                                                 float* __restrict__ st) {
  __shared__ float l[128];
  const int j = threadIdx.x;
  float a0 = 0.f, a1 = 0.f, a2 = 0.f, a3 = 0.f;
  for (int i = 0; i < NC0B; i += 4) {
    a0 += p0[(long long)(i + 0) * 128 + j];
    a1 += p0[(long long)(i + 1) * 128 + j];
    a2 += p0[(long long)(i + 2) * 128 + j];
    a3 += p0[(long long)(i + 3) * 128 + j];
  }
  l[j] = (a0 + a1) + (a2 + a3);
  __syncthreads();
  if (j < 64) {
    const int base = (j >> 4) * 32 + (j & 15);
    const float inv = 1.f / (float)S_;
    float mean = l[base] * inv;
    float ex2  = l[base + 16] * inv;
    float var  = ex2 - mean * mean;
    float sc   = g[j] * rsqrtf(var + EPS_);
    st[j]      = sc;
    st[64 + j] = bt[j] - mean * sc;
  }
}

// --------------------------- k_layer01 -------------------------------------
// Tile = 128 positions. conv0: thread (pg = t&31 -> 4 pos, cg = t>>5 -> 8 ch),
// bn0+relu -> LDS h0[64][128] (32KB, 4 blocks/CU). conv1: same pg, og = t>>5
// -> 2 out-ch; LDS reads are 32-lane-broadcast pairs (conflict-free).
__global__ __launch_bounds__(256, 4) void k_layer01(const float* __restrict__ sv,
                                                    const float* __restrict__ w0T,
                                                    const float* __restrict__ b0,
                                                    const float* __restrict__ st0,
                                                    const float* __restrict__ w1T,
                                                    const float* __restrict__ b1,
                                                    float* __restrict__ y1,
                                                    float* __restrict__ p1) {
  __shared__ float h0[64][128];
  const int t  = threadIdx.x;
  const int pg = t & 31;
  const int cg = t >> 5;              // wave w holds cg {2w, 2w+1}

  float sA[2] = {0.f, 0.f}, qA[2] = {0.f, 0.f};

  for (int tile = blockIdx.x; tile < NL1T; tile += NL1B) {
    const int b  = tile >> 8;                      // 256 tiles per batch
    const int n0 = ((tile & 255) << 7) + (pg << 2);
    const float* xp = sv + ((long long)b * 64) * N_ + n0;

    // ---- conv0: 8 channels (cg*8 + j)
    float4 y[8];
#pragma unroll
    for (int j = 0; j < 8; ++j) {
      float bv = b0[cg * 8 + j];
      y[j].x = bv; y[j].y = bv; y[j].z = bv; y[j].w = bv;
    }
#pragma unroll
    for (int f = 0; f < 64; ++f) {
      const float4 x = *(const float4*)(xp + (long long)f * N_);
      const float* wr = w0T + f * 64 + cg * 8;     // wave-uniform
#pragma unroll
      for (int j = 0; j < 8; ++j) {
        const float w = wr[j];
        y[j].x = fmaf(w, x.x, y[j].x);
        y[j].y = fmaf(w, x.y, y[j].y);
        y[j].z = fmaf(w, x.z, y[j].z);
        y[j].w = fmaf(w, x.w, y[j].w);
      }
    }
    // ---- bn0 + relu -> LDS
#pragma unroll
    for (int j = 0; j < 8; ++j) {
      const int c = cg * 8 + j;
      const float sc = st0[c], sh = st0[64 + c];
      float4 h;
      h.x = fmaf(y[j].x, sc, sh); h.x = h.x > 0.f ? h.x : 0.f;
      h.y = fmaf(y[j].y, sc, sh); h.y = h.y > 0.f ? h.y : 0.f;
      h.z = fmaf(y[j].z, sc, sh); h.z = h.z > 0.f ? h.z : 0.f;
      h.w = fmaf(y[j].w, sc, sh); h.w = h.w > 0.f ? h.w : 0.f;
      *(float4*)&h0[c][pg << 2] = h;
    }
    __syncthreads();

    // ---- conv1: out-ch pair og*2 + {0,1}
    float4 z0, z1;
    {
      const float b10 = b1[cg * 2], b11 = b1[cg * 2 + 1];
      z0.x = b10; z0.y = b10; z0.z = b10; z0.w = b10;
      z1.x = b11; z1.y = b11; z1.z = b11; z1.w = b11;
    }
#pragma unroll
    for (int c = 0; c < 64; ++c) {
      const float4 h = *(const float4*)&h0[c][pg << 2];
      const float* wr = w1T + c * 16 + cg * 2;     // wave-uniform
      const float w0v = wr[0], w1v = wr[1];
      z0.x = fmaf(w0v, h.x, z0.x); z0.y = fmaf(w0v, h.y, z0.y);
      z0.z = fmaf(w0v, h.z, z0.z); z0.w = fmaf(w0v, h.w, z0.w);
      z1.x = fmaf(w1v, h.x, z1.x); z1.y = fmaf(w1v, h.y, z1.y);
      z1.z = fmaf(w1v, h.z, z1.z); z1.w = fmaf(w1v, h.w, z1.w);
    }

    // ---- y1 stores (2 rows x float4)
    float* yo = y1 + ((long long)(b * 16 + cg * 2)) * N_ + n0;
    *(float4*)yo        = z0;
    *(float4*)(yo + N_) = z1;

    // ---- stats1 accumulate
    sA[0] += (z0.x + z0.y) + (z0.z + z0.w);
    qA[0] = fmaf(z0.x, z0.x, fmaf(z0.y, z0.y, fmaf(z0.z, z0.z, fmaf(z0.w, z0.w, qA[0]))));
    sA[1] += (z1.x + z1.y) + (z1.z + z1.w);
    qA[1] = fmaf(z1.x, z1.x, fmaf(z1.y, z1.y, fmaf(z1.z, z1.z, fmaf(z1.w, z1.w, qA[1]))));

    __syncthreads();   // h0 consumed before next tile overwrites it
  }

  // reduce over the 32 pg-lanes (cg is constant within each 32-lane group)
#pragma unroll
  for (int k = 0; k < 2; ++k) {
#pragma unroll
    for (int off = 16; off; off >>= 1) {
      sA[k] += __shfl_down(sA[k], off, 32);
      qA[k] += __shfl_down(qA[k], off, 32);
    }
  }
  if (pg == 0) {
    float* dst = p1 + (long long)blockIdx.x * 32;
    dst[cg * 2 + 0]      = sA[0];
    dst[cg * 2 + 1]      = sA[1];
    dst[16 + cg * 2 + 0] = qA[0];
    dst[16 + cg * 2 + 1] = qA[1];
  }
}

// --------------------------- k_reduce1 -------------------------------------
__global__ __launch_bounds__(64) void k_reduce1(const float* __restrict__ p1,
                                                const float* __restrict__ g,
                                                const float* __restrict__ bt,
                                                float* __restrict__ st) {
  __shared__ float l[32];
  int j = threadIdx.x;
  if (j < 32) {
    float a0 = 0.f, a1 = 0.f, a2 = 0.f, a3 = 0.f;
    for (int i = 0; i < NL1B; i += 4) {
      a0 += p1[(long long)(i + 0) * 32 + j];
      a1 += p1[(long long)(i + 1) * 32 + j];
      a2 += p1[(long long)(i + 2) * 32 + j];
      a3 += p1[(long long)(i + 3) * 32 + j];
    }
    l[j] = (a0 + a1) + (a2 + a3);
  }
  __syncthreads();
  if (j < 16) {
    const float inv = 1.f / (float)S_;
    float mean = l[j] * inv;
    float ex2  = l[16 + j] * inv;
    float var  = ex2 - mean * mean;
    float sc   = g[j] * rsqrtf(var + EPS_);
    st[j]      = sc;
    st[16 + j] = bt[j] - mean * sc;
  }
}

// --------------------------- k_layer2 --------------------------------------
// 256 blocks x 1024 threads; 2 consecutive positions per thread (float2).
__global__ __launch_bounds__(1024) void k_layer2(const float* __restrict__ y1,
                                                 const float* __restrict__ st1,
                                                 const float* __restrict__ w2,
                                                 const float* __restrict__ b2,
                                                 float* __restrict__ y2,
                                                 float* __restrict__ p2,
                                                 int* __restrict__ ghist) {
  __shared__ int hist[NBINS];
  __shared__ float ls[16], lq[16];
  const int t   = threadIdx.x;
  const int blk = blockIdx.x;
  const int b   = blk >> 4;
  const int n0  = ((blk & 15) << 11) | (t << 1);   // 2048 positions per block

#pragma unroll
  for (int i = 0; i < NBINS / 1024; ++i) hist[t + i * 1024] = 0;

  float sc[16], sh[16], w[16];
#pragma unroll
  for (int c = 0; c < 16; ++c) { sc[c] = st1[c]; sh[c] = st1[16 + c]; w[c] = w2[c]; }
  const float bias = b2[0];

  float a0 = bias, a1 = bias;
  const float* base = y1 + ((long long)b * 16) * N_ + n0;
#pragma unroll
  for (int c = 0; c < 16; ++c) {
    float2 v = *(const float2*)(base + (long long)c * N_);
    float h;
    h = fmaf(v.x, sc[c], sh[c]); h = h > 0.f ? h : 0.f; a0 = fmaf(w[c], h, a0);
    h = fmaf(v.y, sc[c], sh[c]); h = h > 0.f ? h : 0.f; a1 = fmaf(w[c], h, a1);
  }
  float2 o; o.x = a0; o.y = a1;
  *(float2*)(y2 + (long long)b * N_ + n0) = o;

  __syncthreads();   // hist zeroed before any atomic

  atomicAdd(&hist[key_map(a0) >> 20], 1);
  atomicAdd(&hist[key_map(a1) >> 20], 1);

  float ss = a0 + a1;
  float sq = fmaf(a0, a0, a1 * a1);
#pragma unroll
  for (int off = 32; off; off >>= 1) {
    ss += __shfl_down(ss, off, 64);
    sq += __shfl_down(sq, off, 64);
  }
  const int wid = t >> 6, lid = t & 63;
  if (lid == 0) { ls[wid] = ss; lq[wid] = sq; }
  __syncthreads();   // covers ls/lq stores AND hist atomics
  if (t == 0) {
    float Sv = 0.f, Qv = 0.f;
#pragma unroll
    for (int i = 0; i < 16; ++i) { Sv += ls[i]; Qv += lq[i]; }
    p2[blk * 2 + 0] = Sv;
    p2[blk * 2 + 1] = Qv;
  }
#pragma unroll
  for (int i = 0; i < NBINS / 1024; ++i) {
    int v = hist[t + i * 1024];
    if (v) atomicAdd(&ghist[b * NBINS + t + i * 1024], v);
  }
}

// --------------------------- k_thresh --------------------------------------
__global__ __launch_bounds__(256) void k_thresh(const int* __restrict__ ghist,
                                                int* __restrict__ Tb) {
  __shared__ int hl[NBINS + NBINS / 64];
  const int t = threadIdx.x, b = blockIdx.x;
  const int* h = ghist + b * NBINS;
  for (int i = t; i < NBINS; i += 256) hl[i + (i >> 6)] = h[i];
  __syncthreads();
  if (t < 64) {
    const int l = t;
    int s = 0;
    for (int j = 0; j < 64; ++j) s += hl[(l * 64 + j) + l];
    int Sv = s;
#pragma unroll
    for (int off = 1; off < 64; off <<= 1) {
      int v = __shfl_down(Sv, off, 64);
      if (l + off < 64) Sv += v;
    }
    unsigned long long m = __ballot(Sv >= K_);
    const int lstar = 63 - __builtin_clzll(m);
    const int tailS = (lstar < 63) ? __shfl(Sv, lstar + 1, 64) : 0;
    int Tj = hl[(lstar * 64 + l) + lstar];
#pragma unroll
    for (int off = 1; off < 64; off <<= 1) {
      int v = __shfl_down(Tj, off, 64);
      if (l + off < 64) Tj += v;
    }
    const int cge = Tj + tailS;
    unsigned long long m2 = __ballot(cge >= K_);
    const int jstar = 63 - __builtin_clzll(m2);
    if (l == 0) Tb[b] = lstar * 64 + jstar;
  }
}

// --------------------------- k_compact -------------------------------------
__global__ __launch_bounds__(1024) void k_compact(const float* __restrict__ y2,
                                                  const int* __restrict__ Tb,
                                                  int* __restrict__ cnt,
                                                  unsigned long long* __restrict__ cand) {
  const int t = threadIdx.x, blk = blockIdx.x;
  const int b  = blk >> 3;
  const int n0 = ((blk & 7) << 12) | (t << 2);
  const int T  = Tb[b];
  float4 v = *(const float4*)(y2 + (long long)b * N_ + n0);
  unsigned long long* cb = cand + (long long)b * CAP;
#define DO_CAND(comp, off)                                                    \
  {                                                                           \
    unsigned u = key_map(comp);                                               \
    if ((int)(u >> 20) >= T) {                                                \
      int slot = atomicAdd(&cnt[b], 1);                                       \
      if (slot < CAP)                                                         \
        cb[slot] = ((unsigned long long)u << 32) |                            \
                   (unsigned)(N_ - 1 - (n0 + off));                           \
    }                                                                         \
  }
  DO_CAND(v.x, 0) DO_CAND(v.y, 1) DO_CAND(v.z, 2) DO_CAND(v.w, 3)
#undef DO_CAND
}

// --------------------------- k_final ---------------------------------------
__global__ __launch_bounds__(64) void k_final(const unsigned long long* __restrict__ cand,
                                              const int* __restrict__ cnt,
                                              const float* __restrict__ p2,
                                              const float* __restrict__ g2,
                                              const float* __restrict__ bt2,
                                              const float* __restrict__ inp,
                                              float* __restrict__ out) {
  const int b = blockIdx.x, l = threadIdx.x;

  // stats2 from 256 block partials (fixed-order tree, same in all blocks)
  float s1 = (p2[2 * l] + p2[2 * (l + 64)]) +
             (p2[2 * (l + 128)] + p2[2 * (l + 192)]);
  float q1 = (p2[2 * l + 1] + p2[2 * (l + 64) + 1]) +
             (p2[2 * (l + 128) + 1] + p2[2 * (l + 192) + 1]);
#pragma unroll
  for (int off = 32; off; off >>= 1) {
    s1 += __shfl_down(s1, off, 64);
    q1 += __shfl_down(q1, off, 64);
  }
  s1 = __shfl(s1, 0, 64);
  q1 = __shfl(q1, 0, 64);
  const float inv = 1.f / (float)S_;
  const float mean = s1 * inv;
  const float var  = q1 * inv - mean * mean;
  const float scale2 = g2[0] * rsqrtf(var + EPS_);
  const float shift2 = bt2[0] - mean * scale2;

  int cn = cnt[b];
  if (cn > CAP) cn = CAP;
  const unsigned long long* cb = cand + (long long)b * CAP;
  unsigned long long k[16];
#pragma unroll
  for (int r = 0; r < 16; ++r) {
    int i = l + r * 64;
    k[r] = (i < cn) ? cb[i] : 0ull;
  }
  unsigned long long cur = 0ull;
#pragma unroll
  for (int r = 0; r < 16; ++r) cur = k[r] > cur ? k[r] : cur;

  int myidx = 0;
  unsigned mymap = 0;
  for (int r = 0; r < K_; ++r) {
    unsigned long long m = cur;
#pragma unroll
    for (int off = 32; off; off >>= 1) {
      unsigned long long o = __shfl_xor(m, off, 64);
      m = o > m ? o : m;
    }
    if (r == l) {
      myidx = N_ - 1 - (int)(m & 0xffffffffu);
      mymap = (unsigned)(m >> 32);
    }
    if (cur == m) {          // exactly one lane (keys unique)
#pragma unroll
      for (int r2 = 0; r2 < 16; ++r2)
        if (k[r2] == m) k[r2] = 0ull;
      unsigned long long c2 = 0ull;
#pragma unroll
      for (int r2 = 0; r2 < 16; ++r2) c2 = k[r2] > c2 ? k[r2] : c2;
      cur = c2;
    }
  }

  unsigned u = mymap;
  u = (u & 0x80000000u) ? (u & 0x7fffffffu) : ~u;
  float v = __uint_as_float(u);
  float scv = fmaf(v, scale2, shift2);
  scv = scv > 0.f ? scv : 0.f;

  const float* ib = inp + ((long long)b * 64) * N_;
#pragma unroll 4
  for (int f = 0; f < 64; ++f)
    out[((long long)b * 65 + f) * 64 + l] = ib[(long long)f * N_ + myidx];
  out[((long long)b * 65 + 64) * 64 + l] = scv;
  out[(long long)B_ * 65 * 64 + b * 64 + l] = (float)myidx;
}

// --------------------------- launch ----------------------------------------
extern "C" void kernel_launch(void* const* d_in, const int* in_sizes, int n_in,
                              void* d_out, int out_size, void* d_ws, size_t ws_size,
                              hipStream_t stream) {
  const float* sv  = (const float*)d_in[0];
  const float* inp = (const float*)d_in[1];
  const float* w0  = (const float*)d_in[2];
  const float* b0  = (const float*)d_in[3];
  const float* w1  = (const float*)d_in[4];
  const float* b1  = (const float*)d_in[5];
  const float* w2  = (const float*)d_in[6];
  const float* b2  = (const float*)d_in[7];
  const float* g0  = (const float*)d_in[8];
  const float* bt0 = (const float*)d_in[9];
  const float* g1  = (const float*)d_in[10];
  const float* bt1 = (const float*)d_in[11];
  const float* g2  = (const float*)d_in[12];
  const float* bt2 = (const float*)d_in[13];
  float* out = (float*)d_out;

  float* ws  = (float*)d_ws;
  float* y1  = ws;                                    // 8388608 floats
  float* y2  = y1 + (size_t)S_ * 16;                  //  524288
  float* p0  = y2 + (size_t)S_;                       //  NC0B*128 = 65536
  float* p1  = p0 + (size_t)NC0B * 128;               //  NL1B*32  = 16384
  float* p2  = p1 + (size_t)NL1B * 32;                //  NB2*2    = 512
  float* st0 = p2 + (size_t)NB2 * 2;                  //  128
  float* st1 = st0 + 128;                             //  32
  float* w0T = st1 + 32;                              //  4096
  float* w1T = w0T + 4096;                            //  1024
  int*   ghist = (int*)(w1T + 1024);                  //  B*NBINS = 65536 ints
  int*   cnt   = ghist + (size_t)B_ * NBINS;          //  16 ints
  int*   Tb    = cnt + 16;                            //  16 ints
  unsigned long long* cand =
      (unsigned long long*)(Tb + 16);                 //  16*CAP u64

  hipMemsetAsync(ghist, 0, ((size_t)B_ * NBINS + 16) * sizeof(int), stream);

  k_prep     <<<1,    256, 0, stream>>>(w0, w1, w0T, w1T);
  k_conv0stat<<<NC0B, 256, 0, stream>>>(sv, w0T, b0, p0);
  k_reduce0  <<<1,    128, 0, stream>>>(p0, g0, bt0, st0);
  k_layer01  <<<NL1B, 256, 0, stream>>>(sv, w0T, b0, st0, w1T, b1, y1, p1);
  k_reduce1  <<<1,     64, 0, stream>>>(p1, g1, bt1, st1);
  k_layer2   <<<NB2, 1024, 0, stream>>>(y1, st1, w2, b2, y2, p2, ghist);
  k_thresh   <<<B_,   256, 0, stream>>>(ghist, Tb);
  k_compact  <<<NBC, 1024, 0, stream>>>(y2, Tb, cnt, cand);
  k_final    <<<B_,    64, 0, stream>>>(cand, cnt, p2, g2, bt2, inp, out);
}

// Round 5
// 305.651 us; speedup vs baseline: 8.4953x; 8.4953x over previous
//
#include <hip/hip_runtime.h>

// ---------------------------------------------------------------------------
// SortNet: 3-layer 1x1-conv MLP (64->64->16->1) with training-mode BatchNorm
// + ReLU, per-batch top-64 over N, gather of input + score.
//
// R5 structure: R2's proven LDS-staged GEMM shape (48 VGPR class, wave-uniform
// weight pointers via readfirstlane, scalar ds_reads). conv0 computed ONCE:
// k_conv0 stores y0 (134 MB, L3-resident) + stats partials; k_bn1 streams y0
// through bn0+relu+conv1. R3/R4 lesson: register-blocked float4 variants with
// >=64 accum VGPRs or non-uniform weight pointers hit a 10-20x codegen cliff.
//
// Fallback (ws_size too small for y0): R2's recompute path, verbatim.
//
// Pipeline (store path): memset, k_prep, k_conv0<true>, k_reduce0, k_bn1,
//   k_reduce1, k_layer2(+hist), k_thresh, k_compact, k_final.
// ---------------------------------------------------------------------------

constexpr int   B_   = 16;
constexpr int   N_   = 32768;
constexpr int   K_   = 64;            // TOP_K
constexpr long long S_ = (long long)B_ * N_;   // 524288
constexpr float EPS_ = 1e-5f;

constexpr int NB0   = 1024;   // k_conv0 blocks (grid-stride over 8192 tiles)
constexpr int T64   = 8192;   // 64-position tiles (S/64)
constexpr int NBN1  = 512;    // k_bn1 blocks (grid-stride over 2048 tiles)
constexpr int NB1   = 2048;   // fallback k_layer01 blocks
constexpr int NB2   = 256;    // k_layer2 blocks (2048 pos each)
constexpr int NBC   = 128;    // k_compact blocks (4096 pos each)
constexpr int NBINS = 4096;   // radix-select bins (key >> 20)
constexpr int CAP   = 1024;   // candidate capacity per batch

__device__ __forceinline__ unsigned key_map(float f) {
  unsigned u = __float_as_uint(f);
  return (u & 0x80000000u) ? ~u : (u | 0x80000000u);
}

// --------------------------- k_prep ----------------------------------------
__global__ __launch_bounds__(256) void k_prep(const float* __restrict__ w0,
                                              const float* __restrict__ w1,
                                              float* __restrict__ w0T,
                                              float* __restrict__ w1T) {
  int t = threadIdx.x;
  for (int e = t; e < 64 * 64; e += 256) {
    int o = e >> 6, f = e & 63;
    w0T[f * 64 + o] = w0[e];          // w0T[f][o] = w0[o][f]
  }
  for (int e = t; e < 16 * 64; e += 256) {
    int o = e >> 6, c = e & 63;
    w1T[c * 16 + o] = w1[e];          // w1T[c][o] = w1[o][c]
  }
}

// --------------------------- k_conv0 ---------------------------------------
// R2 k_stat0 shape: tile = 64 positions staged in LDS; thread (p = t&63,
// cg = t>>6 readfirstlane'd) computes 16 channels of 1 position.
// STORE_Y0: additionally writes y0[b][c][n] (16 coalesced scalar stores).
template <bool STORE_Y0>
__global__ __launch_bounds__(256) void k_conv0(const float* __restrict__ sv,
                                               const float* __restrict__ w0T,
                                               const float* __restrict__ b0,
                                               float* __restrict__ y0,
                                               float* __restrict__ p0) {
  __shared__ float svt[64][64];
  const int t  = threadIdx.x;
  const int p  = t & 63;
  const int cg = __builtin_amdgcn_readfirstlane(t >> 6);  // wave-uniform

  float bb[16];
#pragma unroll
  for (int j = 0; j < 16; ++j) bb[j] = b0[cg * 16 + j];

  float s1[16], s2[16];
#pragma unroll
  for (int j = 0; j < 16; ++j) { s1[j] = 0.f; s2[j] = 0.f; }

  for (int tile = blockIdx.x; tile < T64; tile += NB0) {
    const int b  = tile >> 9;             // 512 tiles per batch
    const int n0 = (tile & 511) << 6;
    const float* src = sv + ((long long)b * 64) * N_ + n0;
    __syncthreads();
#pragma unroll
    for (int q = 0; q < 4; ++q) {
      int e = t + q * 256;                // 1024 float4 per tile
      int f = e >> 4, c4 = (e & 15) << 2;
      *(float4*)&svt[f][c4] = *(const float4*)(src + (long long)f * N_ + c4);
    }
    __syncthreads();

    float y[16];
#pragma unroll
    for (int j = 0; j < 16; ++j) y[j] = bb[j];
    for (int f = 0; f < 64; ++f) {
      float s = svt[f][p];
      const float* wr = w0T + f * 64 + cg * 16;   // wave-uniform -> s_load
#pragma unroll
      for (int j = 0; j < 16; ++j) y[j] = fmaf(wr[j], s, y[j]);
    }
#pragma unroll
    for (int j = 0; j < 16; ++j) {
      s1[j] += y[j];
      s2[j] = fmaf(y[j], y[j], s2[j]);
    }
    if constexpr (STORE_Y0) {
      float* dst = y0 + ((long long)(b * 64 + cg * 16)) * N_ + n0 + p;
#pragma unroll
      for (int j = 0; j < 16; ++j) dst[(long long)j * N_] = y[j];
    }
  }

#pragma unroll
  for (int j = 0; j < 16; ++j) {
#pragma unroll
    for (int off = 32; off; off >>= 1) {
      s1[j] += __shfl_down(s1[j], off, 64);
      s2[j] += __shfl_down(s2[j], off, 64);
    }
  }
  if (p == 0) {
    float* dst = p0 + (long long)blockIdx.x * 128;
#pragma unroll
    for (int j = 0; j < 16; ++j) {
      dst[cg * 16 + j]      = s1[j];
      dst[64 + cg * 16 + j] = s2[j];
    }
  }
}

// --------------------------- k_reduce0 -------------------------------------
__global__ __launch_bounds__(128) void k_reduce0(const float* __restrict__ p0,
                                                 const float* __restrict__ g,
                                                 const float* __restrict__ bt,
                                                 float* __restrict__ st,
                                                 int nb) {
  __shared__ float l[128];
  int j = threadIdx.x;
  float a0 = 0.f, a1 = 0.f, a2 = 0.f, a3 = 0.f;
  for (int i = 0; i < nb; i += 4) {
    a0 += p0[(long long)(i + 0) * 128 + j];
    a1 += p0[(long long)(i + 1) * 128 + j];
    a2 += p0[(long long)(i + 2) * 128 + j];
    a3 += p0[(long long)(i + 3) * 128 + j];
  }
  l[j] = (a0 + a1) + (a2 + a3);
  __syncthreads();
  if (j < 64) {
    const float inv = 1.f / (float)S_;
    float mean = l[j] * inv;
    float ex2  = l[64 + j] * inv;
    float var  = ex2 - mean * mean;
    float sc   = g[j] * rsqrtf(var + EPS_);
    st[j]      = sc;
    st[64 + j] = bt[j] - mean * sc;
  }
}

// --------------------------- k_bn1 (store path) ----------------------------
// 1 position/thread, grid-stride. Streams y0 rows (64 coalesced strided
// loads), bn0+relu, conv1 (1024 FMA), 16 coalesced y1 stores, stats1.
// Live set ~60 floats (z[16]+s1[16]+s2[16]) - R2 class, safe.
__global__ __launch_bounds__(256) void k_bn1(const float* __restrict__ y0,
                                             const float* __restrict__ st0,
                                             const float* __restrict__ w1T,
                                             const float* __restrict__ b1,
                                             float* __restrict__ y1,
                                             float* __restrict__ p1) {
  __shared__ float red[4][32];
  const int t = threadIdx.x;

  float s1[16], s2[16];
#pragma unroll
  for (int j = 0; j < 16; ++j) { s1[j] = 0.f; s2[j] = 0.f; }

  for (int tile = blockIdx.x; tile < 2048; tile += NBN1) {
    const long long pos = (long long)tile * 256 + t;
    const int b = (int)(pos >> 15);
    const int n = (int)(pos & (N_ - 1));
    const float* xp = y0 + ((long long)b * 64) * N_ + n;

    float z[16];
#pragma unroll
    for (int j = 0; j < 16; ++j) z[j] = b1[j];
#pragma unroll 8
    for (int c = 0; c < 64; ++c) {
      float v = xp[(long long)c * N_];
      float h = fmaf(v, st0[c], st0[64 + c]);
      h = h > 0.f ? h : 0.f;
      const float* wr = w1T + c * 16;              // wave-uniform -> s_load
#pragma unroll
      for (int j = 0; j < 16; ++j) z[j] = fmaf(wr[j], h, z[j]);
    }

    float* yo = y1 + ((long long)b * 16) * N_ + n;
#pragma unroll
    for (int j = 0; j < 16; ++j) {
      yo[(long long)j * N_] = z[j];
      s1[j] += z[j];
      s2[j] = fmaf(z[j], z[j], s2[j]);
    }
  }

  const int wid = t >> 6, lid = t & 63;
#pragma unroll
  for (int j = 0; j < 16; ++j) {
    float a = s1[j], q = s2[j];
#pragma unroll
    for (int off = 32; off; off >>= 1) {
      a += __shfl_down(a, off, 64);
      q += __shfl_down(q, off, 64);
    }
    if (lid == 0) { red[wid][j] = a; red[wid][16 + j] = q; }
  }
  __syncthreads();
  if (t < 32)
    p1[(long long)blockIdx.x * 32 + t] =
        (red[0][t] + red[1][t]) + (red[2][t] + red[3][t]);
}

// --------------------------- k_layer01 (fallback, R2 verbatim) -------------
__global__ __launch_bounds__(256) void k_layer01(const float* __restrict__ sv,
                                                 const float* __restrict__ w0T,
                                                 const float* __restrict__ b0,
                                                 const float* __restrict__ st0,
                                                 const float* __restrict__ w1T,
                                                 const float* __restrict__ b1,
                                                 float* __restrict__ y1,
                                                 float* __restrict__ p1) {
  __shared__ float svt[64][64];
  __shared__ float h0[64][64];
  const int t  = threadIdx.x;
  const int p  = t & 63;
  const int cg = __builtin_amdgcn_readfirstlane(t >> 6);

  float bb[16], sc[16], sh[16];
#pragma unroll
  for (int j = 0; j < 16; ++j) {
    bb[j] = b0[cg * 16 + j];
    sc[j] = st0[cg * 16 + j];
    sh[j] = st0[64 + cg * 16 + j];
  }
  float bb1[4];
#pragma unroll
  for (int j = 0; j < 4; ++j) bb1[j] = b1[cg * 4 + j];

  float s1[4], s2[4];
#pragma unroll
  for (int j = 0; j < 4; ++j) { s1[j] = 0.f; s2[j] = 0.f; }

  for (int tile = blockIdx.x; tile < T64; tile += NB1) {
    const int b  = tile >> 9;
    const int n0 = (tile & 511) << 6;
    const float* src = sv + ((long long)b * 64) * N_ + n0;
    __syncthreads();
#pragma unroll
    for (int q = 0; q < 4; ++q) {
      int e = t + q * 256;
      int f = e >> 4, c4 = (e & 15) << 2;
      *(float4*)&svt[f][c4] = *(const float4*)(src + (long long)f * N_ + c4);
    }
    __syncthreads();

    float y[16];
#pragma unroll
    for (int j = 0; j < 16; ++j) y[j] = bb[j];
    for (int f = 0; f < 64; ++f) {
      float s = svt[f][p];
      const float* wr = w0T + f * 64 + cg * 16;
#pragma unroll
      for (int j = 0; j < 16; ++j) y[j] = fmaf(wr[j], s, y[j]);
    }
#pragma unroll
    for (int j = 0; j < 16; ++j) {
      float h = fmaf(y[j], sc[j], sh[j]);
      h0[cg * 16 + j][p] = h > 0.f ? h : 0.f;
    }
    __syncthreads();

    float z[4];
#pragma unroll
    for (int j = 0; j < 4; ++j) z[j] = bb1[j];
    for (int f = 0; f < 64; ++f) {
      float h = h0[f][p];
      const float* wr = w1T + f * 16 + cg * 4;
#pragma unroll
      for (int j = 0; j < 4; ++j) z[j] = fmaf(wr[j], h, z[j]);
    }
#pragma unroll
    for (int j = 0; j < 4; ++j) {
      s1[j] += z[j];
      s2[j] = fmaf(z[j], z[j], s2[j]);
      y1[((long long)b * 16 + cg * 4 + j) * N_ + n0 + p] = z[j];
    }
  }

#pragma unroll
  for (int j = 0; j < 4; ++j) {
#pragma unroll
    for (int off = 32; off; off >>= 1) {
      s1[j] += __shfl_down(s1[j], off, 64);
      s2[j] += __shfl_down(s2[j], off, 64);
    }
  }
  if (p == 0) {
    float* dst = p1 + (long long)blockIdx.x * 32;
#pragma unroll
    for (int j = 0; j < 4; ++j) {
      dst[cg * 4 + j]      = s1[j];
      dst[16 + cg * 4 + j] = s2[j];
    }
  }
}

// --------------------------- k_reduce1 -------------------------------------
__global__ __launch_bounds__(64) void k_reduce1(const float* __restrict__ p1,
                                                const float* __restrict__ g,
                                                const float* __restrict__ bt,
                                                float* __restrict__ st,
                                                int nb) {
  __shared__ float l[32];
  int j = threadIdx.x;
  if (j < 32) {
    float a0 = 0.f, a1 = 0.f, a2 = 0.f, a3 = 0.f;
    for (int i = 0; i < nb; i += 4) {
      a0 += p1[(long long)(i + 0) * 32 + j];
      a1 += p1[(long long)(i + 1) * 32 + j];
      a2 += p1[(long long)(i + 2) * 32 + j];
      a3 += p1[(long long)(i + 3) * 32 + j];
    }
    l[j] = (a0 + a1) + (a2 + a3);
  }
  __syncthreads();
  if (j < 16) {
    const float inv = 1.f / (float)S_;
    float mean = l[j] * inv;
    float ex2  = l[16 + j] * inv;
    float var  = ex2 - mean * mean;
    float sc   = g[j] * rsqrtf(var + EPS_);
    st[j]      = sc;
    st[16 + j] = bt[j] - mean * sc;
  }
}

// --------------------------- k_layer2 --------------------------------------
__global__ __launch_bounds__(1024) void k_layer2(const float* __restrict__ y1,
                                                 const float* __restrict__ st1,
                                                 const float* __restrict__ w2,
                                                 const float* __restrict__ b2,
                                                 float* __restrict__ y2,
                                                 float* __restrict__ p2,
                                                 int* __restrict__ ghist) {
  __shared__ int hist[NBINS];
  __shared__ float ls[16], lq[16];
  const int t   = threadIdx.x;
  const int blk = blockIdx.x;
  const int b   = blk >> 4;
  const int n0  = ((blk & 15) << 11) | (t << 1);   // 2048 positions per block

#pragma unroll
  for (int i = 0; i < NBINS / 1024; ++i) hist[t + i * 1024] = 0;

  float sc[16], sh[16], w[16];
#pragma unroll
  for (int c = 0; c < 16; ++c) { sc[c] = st1[c]; sh[c] = st1[16 + c]; w[c] = w2[c]; }
  const float bias = b2[0];

  float a0 = bias, a1 = bias;
  const float* base = y1 + ((long long)b * 16) * N_ + n0;
#pragma unroll
  for (int c = 0; c < 16; ++c) {
    float2 v = *(const float2*)(base + (long long)c * N_);
    float h;
    h = fmaf(v.x, sc[c], sh[c]); h = h > 0.f ? h : 0.f; a0 = fmaf(w[c], h, a0);
    h = fmaf(v.y, sc[c], sh[c]); h = h > 0.f ? h : 0.f; a1 = fmaf(w[c], h, a1);
  }
  float2 o; o.x = a0; o.y = a1;
  *(float2*)(y2 + (long long)b * N_ + n0) = o;

  __syncthreads();   // hist zeroed before any atomic

  atomicAdd(&hist[key_map(a0) >> 20], 1);
  atomicAdd(&hist[key_map(a1) >> 20], 1);

  float ss = a0 + a1;
  float sq = fmaf(a0, a0, a1 * a1);
#pragma unroll
  for (int off = 32; off; off >>= 1) {
    ss += __shfl_down(ss, off, 64);
    sq += __shfl_down(sq, off, 64);
  }
  const int wid = t >> 6, lid = t & 63;
  if (lid == 0) { ls[wid] = ss; lq[wid] = sq; }
  __syncthreads();   // covers ls/lq stores AND hist atomics
  if (t == 0) {
    float Sv = 0.f, Qv = 0.f;
#pragma unroll
    for (int i = 0; i < 16; ++i) { Sv += ls[i]; Qv += lq[i]; }
    p2[blk * 2 + 0] = Sv;
    p2[blk * 2 + 1] = Qv;
  }
#pragma unroll
  for (int i = 0; i < NBINS / 1024; ++i) {
    int v = hist[t + i * 1024];
    if (v) atomicAdd(&ghist[b * NBINS + t + i * 1024], v);
  }
}

// --------------------------- k_thresh --------------------------------------
__global__ __launch_bounds__(256) void k_thresh(const int* __restrict__ ghist,
                                                int* __restrict__ Tb) {
  __shared__ int hl[NBINS + NBINS / 64];
  const int t = threadIdx.x, b = blockIdx.x;
  const int* h = ghist + b * NBINS;
  for (int i = t; i < NBINS; i += 256) hl[i + (i >> 6)] = h[i];
  __syncthreads();
  if (t < 64) {
    const int l = t;
    int s = 0;
    for (int j = 0; j < 64; ++j) s += hl[(l * 64 + j) + l];
    int Sv = s;
#pragma unroll
    for (int off = 1; off < 64; off <<= 1) {
      int v = __shfl_down(Sv, off, 64);
      if (l + off < 64) Sv += v;
    }
    unsigned long long m = __ballot(Sv >= K_);
    const int lstar = 63 - __builtin_clzll(m);
    const int tailS = (lstar < 63) ? __shfl(Sv, lstar + 1, 64) : 0;
    int Tj = hl[(lstar * 64 + l) + lstar];
#pragma unroll
    for (int off = 1; off < 64; off <<= 1) {
      int v = __shfl_down(Tj, off, 64);
      if (l + off < 64) Tj += v;
    }
    const int cge = Tj + tailS;
    unsigned long long m2 = __ballot(cge >= K_);
    const int jstar = 63 - __builtin_clzll(m2);
    if (l == 0) Tb[b] = lstar * 64 + jstar;
  }
}

// --------------------------- k_compact -------------------------------------
__global__ __launch_bounds__(1024) void k_compact(const float* __restrict__ y2,
                                                  const int* __restrict__ Tb,
                                                  int* __restrict__ cnt,
                                                  unsigned long long* __restrict__ cand) {
  const int t = threadIdx.x, blk = blockIdx.x;
  const int b  = blk >> 3;
  const int n0 = ((blk & 7) << 12) | (t << 2);
  const int T  = Tb[b];
  float4 v = *(const float4*)(y2 + (long long)b * N_ + n0);
  unsigned long long* cb = cand + (long long)b * CAP;
#define DO_CAND(comp, off)                                                    \
  {                                                                           \
    unsigned u = key_map(comp);                                               \
    if ((int)(u >> 20) >= T) {                                                \
      int slot = atomicAdd(&cnt[b], 1);                                       \
      if (slot < CAP)                                                         \
        cb[slot] = ((unsigned long long)u << 32) |                            \
                   (unsigned)(N_ - 1 - (n0 + off));                           \
    }                                                                         \
  }
  DO_CAND(v.x, 0) DO_CAND(v.y, 1) DO_CAND(v.z, 2) DO_CAND(v.w, 3)
#undef DO_CAND
}

// --------------------------- k_final ---------------------------------------
__global__ __launch_bounds__(64) void k_final(const unsigned long long* __restrict__ cand,
                                              const int* __restrict__ cnt,
                                              const float* __restrict__ p2,
                                              const float* __restrict__ g2,
                                              const float* __restrict__ bt2,
                                              const float* __restrict__ inp,
                                              float* __restrict__ out) {
  const int b = blockIdx.x, l = threadIdx.x;

  // stats2 from 256 block partials (fixed-order tree, same in all blocks)
  float s1 = (p2[2 * l] + p2[2 * (l + 64)]) +
             (p2[2 * (l + 128)] + p2[2 * (l + 192)]);
  float q1 = (p2[2 * l + 1] + p2[2 * (l + 64) + 1]) +
             (p2[2 * (l + 128) + 1] + p2[2 * (l + 192) + 1]);
#pragma unroll
  for (int off = 32; off; off >>= 1) {
    s1 += __shfl_down(s1, off, 64);
    q1 += __shfl_down(q1, off, 64);
  }
  s1 = __shfl(s1, 0, 64);
  q1 = __shfl(q1, 0, 64);
  const float inv = 1.f / (float)S_;
  const float mean = s1 * inv;
  const float var  = q1 * inv - mean * mean;
  const float scale2 = g2[0] * rsqrtf(var + EPS_);
  const float shift2 = bt2[0] - mean * scale2;

  int cn = cnt[b];
  if (cn > CAP) cn = CAP;
  const unsigned long long* cb = cand + (long long)b * CAP;
  unsigned long long k[16];
#pragma unroll
  for (int r = 0; r < 16; ++r) {
    int i = l + r * 64;
    k[r] = (i < cn) ? cb[i] : 0ull;
  }
  unsigned long long cur = 0ull;
#pragma unroll
  for (int r = 0; r < 16; ++r) cur = k[r] > cur ? k[r] : cur;

  int myidx = 0;
  unsigned mymap = 0;
  for (int r = 0; r < K_; ++r) {
    unsigned long long m = cur;
#pragma unroll
    for (int off = 32; off; off >>= 1) {
      unsigned long long o = __shfl_xor(m, off, 64);
      m = o > m ? o : m;
    }
    if (r == l) {
      myidx = N_ - 1 - (int)(m & 0xffffffffu);
      mymap = (unsigned)(m >> 32);
    }
    if (cur == m) {          // exactly one lane (keys unique)
#pragma unroll
      for (int r2 = 0; r2 < 16; ++r2)
        if (k[r2] == m) k[r2] = 0ull;
      unsigned long long c2 = 0ull;
#pragma unroll
      for (int r2 = 0; r2 < 16; ++r2) c2 = k[r2] > c2 ? k[r2] : c2;
      cur = c2;
    }
  }

  unsigned u = mymap;
  u = (u & 0x80000000u) ? (u & 0x7fffffffu) : ~u;
  float v = __uint_as_float(u);
  float scv = fmaf(v, scale2, shift2);
  scv = scv > 0.f ? scv : 0.f;

  const float* ib = inp + ((long long)b * 64) * N_;
#pragma unroll 4
  for (int f = 0; f < 64; ++f)
    out[((long long)b * 65 + f) * 64 + l] = ib[(long long)f * N_ + myidx];
  out[((long long)b * 65 + 64) * 64 + l] = scv;
  out[(long long)B_ * 65 * 64 + b * 64 + l] = (float)myidx;
}

// --------------------------- launch ----------------------------------------
extern "C" void kernel_launch(void* const* d_in, const int* in_sizes, int n_in,
                              void* d_out, int out_size, void* d_ws, size_t ws_size,
                              hipStream_t stream) {
  const float* sv  = (const float*)d_in[0];
  const float* inp = (const float*)d_in[1];
  const float* w0  = (const float*)d_in[2];
  const float* b0  = (const float*)d_in[3];
  const float* w1  = (const float*)d_in[4];
  const float* b1  = (const float*)d_in[5];
  const float* w2  = (const float*)d_in[6];
  const float* b2  = (const float*)d_in[7];
  const float* g0  = (const float*)d_in[8];
  const float* bt0 = (const float*)d_in[9];
  const float* g1  = (const float*)d_in[10];
  const float* bt1 = (const float*)d_in[11];
  const float* g2  = (const float*)d_in[12];
  const float* bt2 = (const float*)d_in[13];
  float* out = (float*)d_out;

  float* ws  = (float*)d_ws;
  float* y1  = ws;                                    // S*16    = 8388608
  float* y2  = y1 + (size_t)S_ * 16;                  // S       =  524288
  float* p0  = y2 + (size_t)S_;                       // 1024*128= 131072
  float* p1  = p0 + (size_t)NB0 * 128;                // 2048*32 =  65536
  float* p2  = p1 + (size_t)NB1 * 32;                 // 256*2   =     512
  float* st0 = p2 + (size_t)NB2 * 2;                  // 128
  float* st1 = st0 + 128;                             // 32
  float* w0T = st1 + 32;                              // 4096
  float* w1T = w0T + 4096;                            // 1024
  int*   ghist = (int*)(w1T + 1024);                  // 16*4096 ints
  int*   cnt   = ghist + (size_t)B_ * NBINS;          // 16 ints
  int*   Tb    = cnt + 16;                            // 16 ints
  unsigned long long* cand =
      (unsigned long long*)(Tb + 16);                 // 16*CAP u64
  float* y0 = (float*)(cand + (size_t)B_ * CAP);      // S*64 = 33554432 floats

  const size_t need_bytes =
      (size_t)((const char*)(y0 + (size_t)S_ * 64) - (const char*)d_ws);
  const bool store_path = ws_size >= need_bytes;

  hipMemsetAsync(ghist, 0, ((size_t)B_ * NBINS + 16) * sizeof(int), stream);

  k_prep<<<1, 256, 0, stream>>>(w0, w1, w0T, w1T);

  if (store_path) {
    k_conv0<true><<<NB0, 256, 0, stream>>>(sv, w0T, b0, y0, p0);
    k_reduce0<<<1, 128, 0, stream>>>(p0, g0, bt0, st0, NB0);
    k_bn1<<<NBN1, 256, 0, stream>>>(y0, st0, w1T, b1, y1, p1);
    k_reduce1<<<1, 64, 0, stream>>>(p1, g1, bt1, st1, NBN1);
  } else {
    k_conv0<false><<<NB0, 256, 0, stream>>>(sv, w0T, b0, nullptr, p0);
    k_reduce0<<<1, 128, 0, stream>>>(p0, g0, bt0, st0, NB0);
    k_layer01<<<NB1, 256, 0, stream>>>(sv, w0T, b0, st0, w1T, b1, y1, p1);
    k_reduce1<<<1, 64, 0, stream>>>(p1, g1, bt1, st1, NB1);
  }

  k_layer2 <<<NB2, 1024, 0, stream>>>(y1, st1, w2, b2, y2, p2, ghist);
  k_thresh <<<B_,   256, 0, stream>>>(ghist, Tb);
  k_compact<<<NBC, 1024, 0, stream>>>(y2, Tb, cnt, cand);
  k_final  <<<B_,    64, 0, stream>>>(cand, cnt, p2, g2, bt2, inp, out);
}

// Round 6
// 292.836 us; speedup vs baseline: 8.8671x; 1.0438x over previous
//
#include <hip/hip_runtime.h>

// ---------------------------------------------------------------------------
// SortNet: 3-layer 1x1-conv MLP (64->64->16->1) with training-mode BatchNorm
// + ReLU, per-batch top-64 over N, gather of input + score.
//
// R6: recompute structure (no y0 store - R5 showed it loses). Hot GEMMs use
// R2's proven shape (LDS tile + readfirstlane'd channel group -> wave-uniform
// s_load weights) upgraded to 2 positions/thread (float2 acc, ds_read_b64):
// 32 FMA per LDS read, half the barriers per FMA, live VGPR ~80 (below the
// R3/R4 remat cliff at ~128). k_layer01 reuses one 32KB LDS buffer for both
// the sv tile and h0 (5 blocks/CU). Reduce kernels parallelized (were serial
// latency-bound, ~20 us).
//
// Pipeline: memset, k_prep, k_stat0, k_reduce0, k_layer01, k_reduce1,
//   k_layer2(+hist), k_thresh, k_compact, k_final. All deterministic.
// ---------------------------------------------------------------------------

constexpr int   B_   = 16;
constexpr int   N_   = 32768;
constexpr int   K_   = 64;            // TOP_K
constexpr long long S_ = (long long)B_ * N_;   // 524288
constexpr float EPS_ = 1e-5f;

constexpr int T128  = 4096;   // 128-position tiles (S/128)
constexpr int NB0   = 2048;   // k_stat0 blocks (2 tiles each)
constexpr int NB1   = 2048;   // k_layer01 blocks (2 tiles each)
constexpr int NB2   = 256;    // k_layer2 blocks (2048 pos each)
constexpr int NBC   = 128;    // k_compact blocks (4096 pos each)
constexpr int NBINS = 4096;   // radix-select bins (key >> 20)
constexpr int CAP   = 1024;   // candidate capacity per batch

__device__ __forceinline__ unsigned key_map(float f) {
  unsigned u = __float_as_uint(f);
  return (u & 0x80000000u) ? ~u : (u | 0x80000000u);
}

// --------------------------- k_prep ----------------------------------------
__global__ __launch_bounds__(256) void k_prep(const float* __restrict__ w0,
                                              const float* __restrict__ w1,
                                              float* __restrict__ w0T,
                                              float* __restrict__ w1T) {
  int t = threadIdx.x;
  for (int e = t; e < 64 * 64; e += 256) {
    int o = e >> 6, f = e & 63;
    w0T[f * 64 + o] = w0[e];          // w0T[f][o] = w0[o][f]
  }
  for (int e = t; e < 16 * 64; e += 256) {
    int o = e >> 6, c = e & 63;
    w1T[c * 16 + o] = w1[e];          // w1T[c][o] = w1[o][c]
  }
}

// --------------------------- k_stat0 ---------------------------------------
// Tile = 128 positions in LDS. Thread (p = t&63 -> position pair 2p..2p+1,
// cg = t>>6 readfirstlane'd -> 16 channels). Per f: 1 ds_read_b64 + 32 FMA
// from scalar-cached weights. Live: y[16]x2 + s1/s2[16] ~ 80 VGPR.
__global__ __launch_bounds__(256) void k_stat0(const float* __restrict__ sv,
                                               const float* __restrict__ w0T,
                                               const float* __restrict__ b0,
                                               float* __restrict__ p0) {
  __shared__ float svt[64][128];
  const int t  = threadIdx.x;
  const int p  = t & 63;
  const int cg = __builtin_amdgcn_readfirstlane(t >> 6);  // wave-uniform

  float bb[16];
#pragma unroll
  for (int j = 0; j < 16; ++j) bb[j] = b0[cg * 16 + j];

  float s1[16], s2[16];
#pragma unroll
  for (int j = 0; j < 16; ++j) { s1[j] = 0.f; s2[j] = 0.f; }

  for (int tile = blockIdx.x; tile < T128; tile += NB0) {
    const int b  = tile >> 8;             // 256 tiles per batch
    const int n0 = (tile & 255) << 7;
    const float* src = sv + ((long long)b * 64) * N_ + n0;
    __syncthreads();
#pragma unroll
    for (int q = 0; q < 8; ++q) {
      int e = t + q * 256;                // 2048 float4 per tile
      int f = e >> 5, c4 = (e & 31) << 2;
      *(float4*)&svt[f][c4] = *(const float4*)(src + (long long)f * N_ + c4);
    }
    __syncthreads();

    float2 y[16];
#pragma unroll
    for (int j = 0; j < 16; ++j) { y[j].x = bb[j]; y[j].y = bb[j]; }
    for (int f = 0; f < 64; ++f) {
      const float2 x = *(const float2*)&svt[f][p << 1];
      const float* wr = w0T + f * 64 + cg * 16;   // wave-uniform -> s_load
#pragma unroll
      for (int j = 0; j < 16; ++j) {
        y[j].x = fmaf(wr[j], x.x, y[j].x);
        y[j].y = fmaf(wr[j], x.y, y[j].y);
      }
    }
#pragma unroll
    for (int j = 0; j < 16; ++j) {
      s1[j] += y[j].x + y[j].y;
      s2[j] = fmaf(y[j].x, y[j].x, fmaf(y[j].y, y[j].y, s2[j]));
    }
  }

#pragma unroll
  for (int j = 0; j < 16; ++j) {
#pragma unroll
    for (int off = 32; off; off >>= 1) {
      s1[j] += __shfl_down(s1[j], off, 64);
      s2[j] += __shfl_down(s2[j], off, 64);
    }
  }
  if (p == 0) {
    float* dst = p0 + (long long)blockIdx.x * 128;
#pragma unroll
    for (int j = 0; j < 16; ++j) {
      dst[cg * 16 + j]      = s1[j];
      dst[64 + cg * 16 + j] = s2[j];
    }
  }
}

// --------------------------- k_reduce0 -------------------------------------
// Parallel: 1024 threads, 8 groups x 128 slots; 4 independent accumulators.
__global__ __launch_bounds__(1024) void k_reduce0(const float* __restrict__ p0,
                                                  const float* __restrict__ g,
                                                  const float* __restrict__ bt,
                                                  float* __restrict__ st) {
  __shared__ float l[8][128];
  const int t = threadIdx.x;
  const int j = t & 127, grp = t >> 7;
  float a0 = 0.f, a1 = 0.f, a2 = 0.f, a3 = 0.f;
  for (int i = grp; i < 512; i += 8) {
    a0 += p0[(long long)i * 128 + j];
    a1 += p0[(long long)(i + 512) * 128 + j];
    a2 += p0[(long long)(i + 1024) * 128 + j];
    a3 += p0[(long long)(i + 1536) * 128 + j];
  }
  l[grp][j] = (a0 + a1) + (a2 + a3);
  __syncthreads();
  if (t < 128) {
    float v = ((l[0][t] + l[1][t]) + (l[2][t] + l[3][t])) +
              ((l[4][t] + l[5][t]) + (l[6][t] + l[7][t]));
    l[0][t] = v;
  }
  __syncthreads();
  if (t < 64) {
    const float inv = 1.f / (float)S_;
    float mean = l[0][t] * inv;
    float ex2  = l[0][64 + t] * inv;
    float var  = ex2 - mean * mean;
    float sc   = g[t] * rsqrtf(var + EPS_);
    st[t]      = sc;
    st[64 + t] = bt[t] - mean * sc;
  }
}

// --------------------------- k_layer01 -------------------------------------
// Tile = 128 positions, ONE 32KB LDS buffer reused (sv tile, then h0).
// conv0: thread (p, cg) -> 2 pos x 16 ch (2048 FMA); bn0+relu -> buf;
// conv1: thread -> 2 pos x 4 out-ch (512 FMA); y1 stores + stats1.
__global__ __launch_bounds__(256) void k_layer01(const float* __restrict__ sv,
                                                 const float* __restrict__ w0T,
                                                 const float* __restrict__ b0,
                                                 const float* __restrict__ st0,
                                                 const float* __restrict__ w1T,
                                                 const float* __restrict__ b1,
                                                 float* __restrict__ y1,
                                                 float* __restrict__ p1) {
  __shared__ float buf[64][128];
  const int t  = threadIdx.x;
  const int p  = t & 63;
  const int cg = __builtin_amdgcn_readfirstlane(t >> 6);

  float bb[16], sc[16], sh[16];
#pragma unroll
  for (int j = 0; j < 16; ++j) {
    bb[j] = b0[cg * 16 + j];
    sc[j] = st0[cg * 16 + j];
    sh[j] = st0[64 + cg * 16 + j];
  }
  float bb1[4];
#pragma unroll
  for (int j = 0; j < 4; ++j) bb1[j] = b1[cg * 4 + j];

  float sA[4], qA[4];
#pragma unroll
  for (int j = 0; j < 4; ++j) { sA[j] = 0.f; qA[j] = 0.f; }

  for (int tile = blockIdx.x; tile < T128; tile += NB1) {
    const int b  = tile >> 8;
    const int n0 = (tile & 255) << 7;
    const float* src = sv + ((long long)b * 64) * N_ + n0;
    __syncthreads();                      // buf free (prev conv1 done)
#pragma unroll
    for (int q = 0; q < 8; ++q) {
      int e = t + q * 256;
      int f = e >> 5, c4 = (e & 31) << 2;
      *(float4*)&buf[f][c4] = *(const float4*)(src + (long long)f * N_ + c4);
    }
    __syncthreads();

    // ---- conv0 (reads all rows of buf)
    float2 y[16];
#pragma unroll
    for (int j = 0; j < 16; ++j) { y[j].x = bb[j]; y[j].y = bb[j]; }
    for (int f = 0; f < 64; ++f) {
      const float2 x = *(const float2*)&buf[f][p << 1];
      const float* wr = w0T + f * 64 + cg * 16;   // wave-uniform
#pragma unroll
      for (int j = 0; j < 16; ++j) {
        y[j].x = fmaf(wr[j], x.x, y[j].x);
        y[j].y = fmaf(wr[j], x.y, y[j].y);
      }
    }
    __syncthreads();                      // all conv0 reads done

    // ---- bn0 + relu -> buf (h0)
#pragma unroll
    for (int j = 0; j < 16; ++j) {
      float2 h;
      h.x = fmaf(y[j].x, sc[j], sh[j]); h.x = h.x > 0.f ? h.x : 0.f;
      h.y = fmaf(y[j].y, sc[j], sh[j]); h.y = h.y > 0.f ? h.y : 0.f;
      *(float2*)&buf[cg * 16 + j][p << 1] = h;
    }
    __syncthreads();                      // h0 complete

    // ---- conv1: 2 pos x 4 out-ch
    float2 z[4];
#pragma unroll
    for (int j = 0; j < 4; ++j) { z[j].x = bb1[j]; z[j].y = bb1[j]; }
    for (int c = 0; c < 64; ++c) {
      const float2 h = *(const float2*)&buf[c][p << 1];
      const float* wr = w1T + c * 16 + cg * 4;    // wave-uniform
#pragma unroll
      for (int j = 0; j < 4; ++j) {
        z[j].x = fmaf(wr[j], h.x, z[j].x);
        z[j].y = fmaf(wr[j], h.y, z[j].y);
      }
    }

    // ---- y1 stores + stats1
    float* yo = y1 + ((long long)(b * 16 + cg * 4)) * N_ + n0 + (p << 1);
#pragma unroll
    for (int j = 0; j < 4; ++j) {
      *(float2*)(yo + (long long)j * N_) = z[j];
      sA[j] += z[j].x + z[j].y;
      qA[j] = fmaf(z[j].x, z[j].x, fmaf(z[j].y, z[j].y, qA[j]));
    }
  }

#pragma unroll
  for (int j = 0; j < 4; ++j) {
#pragma unroll
    for (int off = 32; off; off >>= 1) {
      sA[j] += __shfl_down(sA[j], off, 64);
      qA[j] += __shfl_down(qA[j], off, 64);
    }
  }
  if (p == 0) {
    float* dst = p1 + (long long)blockIdx.x * 32;
#pragma unroll
    for (int j = 0; j < 4; ++j) {
      dst[cg * 4 + j]      = sA[j];
      dst[16 + cg * 4 + j] = qA[j];
    }
  }
}

// --------------------------- k_reduce1 -------------------------------------
// Parallel: 1024 threads, 32 groups x 32 slots.
__global__ __launch_bounds__(1024) void k_reduce1(const float* __restrict__ p1,
                                                  const float* __restrict__ g,
                                                  const float* __restrict__ bt,
                                                  float* __restrict__ st) {
  __shared__ float l[32][32];
  const int t = threadIdx.x;
  const int j = t & 31, grp = t >> 5;
  float a0 = 0.f, a1 = 0.f;
  for (int i = grp; i < 1024; i += 32) {
    a0 += p1[(long long)i * 32 + j];
    a1 += p1[(long long)(i + 1024) * 32 + j];
  }
  l[grp][j] = a0 + a1;
  __syncthreads();
  if (t < 32) {
    float v = 0.f;
#pragma unroll
    for (int g2 = 0; g2 < 32; ++g2) v += l[g2][t];
    l[0][t] = v;
  }
  __syncthreads();
  if (t < 16) {
    const float inv = 1.f / (float)S_;
    float mean = l[0][t] * inv;
    float ex2  = l[0][16 + t] * inv;
    float var  = ex2 - mean * mean;
    float sc   = g[t] * rsqrtf(var + EPS_);
    st[t]      = sc;
    st[16 + t] = bt[t] - mean * sc;
  }
}

// --------------------------- k_layer2 --------------------------------------
__global__ __launch_bounds__(1024) void k_layer2(const float* __restrict__ y1,
                                                 const float* __restrict__ st1,
                                                 const float* __restrict__ w2,
                                                 const float* __restrict__ b2,
                                                 float* __restrict__ y2,
                                                 float* __restrict__ p2,
                                                 int* __restrict__ ghist) {
  __shared__ int hist[NBINS];
  __shared__ float ls[16], lq[16];
  const int t   = threadIdx.x;
  const int blk = blockIdx.x;
  const int b   = blk >> 4;
  const int n0  = ((blk & 15) << 11) | (t << 1);   // 2048 positions per block

#pragma unroll
  for (int i = 0; i < NBINS / 1024; ++i) hist[t + i * 1024] = 0;

  float sc[16], sh[16], w[16];
#pragma unroll
  for (int c = 0; c < 16; ++c) { sc[c] = st1[c]; sh[c] = st1[16 + c]; w[c] = w2[c]; }
  const float bias = b2[0];

  float a0 = bias, a1 = bias;
  const float* base = y1 + ((long long)b * 16) * N_ + n0;
#pragma unroll
  for (int c = 0; c < 16; ++c) {
    float2 v = *(const float2*)(base + (long long)c * N_);
    float h;
    h = fmaf(v.x, sc[c], sh[c]); h = h > 0.f ? h : 0.f; a0 = fmaf(w[c], h, a0);
    h = fmaf(v.y, sc[c], sh[c]); h = h > 0.f ? h : 0.f; a1 = fmaf(w[c], h, a1);
  }
  float2 o; o.x = a0; o.y = a1;
  *(float2*)(y2 + (long long)b * N_ + n0) = o;

  __syncthreads();   // hist zeroed before any atomic

  atomicAdd(&hist[key_map(a0) >> 20], 1);
  atomicAdd(&hist[key_map(a1) >> 20], 1);

  float ss = a0 + a1;
  float sq = fmaf(a0, a0, a1 * a1);
#pragma unroll
  for (int off = 32; off; off >>= 1) {
    ss += __shfl_down(ss, off, 64);
    sq += __shfl_down(sq, off, 64);
  }
  const int wid = t >> 6, lid = t & 63;
  if (lid == 0) { ls[wid] = ss; lq[wid] = sq; }
  __syncthreads();   // covers ls/lq stores AND hist atomics
  if (t == 0) {
    float Sv = 0.f, Qv = 0.f;
#pragma unroll
    for (int i = 0; i < 16; ++i) { Sv += ls[i]; Qv += lq[i]; }
    p2[blk * 2 + 0] = Sv;
    p2[blk * 2 + 1] = Qv;
  }
#pragma unroll
  for (int i = 0; i < NBINS / 1024; ++i) {
    int v = hist[t + i * 1024];
    if (v) atomicAdd(&ghist[b * NBINS + t + i * 1024], v);
  }
}

// --------------------------- k_thresh --------------------------------------
__global__ __launch_bounds__(256) void k_thresh(const int* __restrict__ ghist,
                                                int* __restrict__ Tb) {
  __shared__ int hl[NBINS + NBINS / 64];
  const int t = threadIdx.x, b = blockIdx.x;
  const int* h = ghist + b * NBINS;
  for (int i = t; i < NBINS; i += 256) hl[i + (i >> 6)] = h[i];
  __syncthreads();
  if (t < 64) {
    const int l = t;
    int s = 0;
    for (int j = 0; j < 64; ++j) s += hl[(l * 64 + j) + l];
    int Sv = s;
#pragma unroll
    for (int off = 1; off < 64; off <<= 1) {
      int v = __shfl_down(Sv, off, 64);
      if (l + off < 64) Sv += v;
    }
    unsigned long long m = __ballot(Sv >= K_);
    const int lstar = 63 - __builtin_clzll(m);
    const int tailS = (lstar < 63) ? __shfl(Sv, lstar + 1, 64) : 0;
    int Tj = hl[(lstar * 64 + l) + lstar];
#pragma unroll
    for (int off = 1; off < 64; off <<= 1) {
      int v = __shfl_down(Tj, off, 64);
      if (l + off < 64) Tj += v;
    }
    const int cge = Tj + tailS;
    unsigned long long m2 = __ballot(cge >= K_);
    const int jstar = 63 - __builtin_clzll(m2);
    if (l == 0) Tb[b] = lstar * 64 + jstar;
  }
}

// --------------------------- k_compact -------------------------------------
__global__ __launch_bounds__(1024) void k_compact(const float* __restrict__ y2,
                                                  const int* __restrict__ Tb,
                                                  int* __restrict__ cnt,
                                                  unsigned long long* __restrict__ cand) {
  const int t = threadIdx.x, blk = blockIdx.x;
  const int b  = blk >> 3;
  const int n0 = ((blk & 7) << 12) | (t << 2);
  const int T  = Tb[b];
  float4 v = *(const float4*)(y2 + (long long)b * N_ + n0);
  unsigned long long* cb = cand + (long long)b * CAP;
#define DO_CAND(comp, off)                                                    \
  {                                                                           \
    unsigned u = key_map(comp);                                               \
    if ((int)(u >> 20) >= T) {                                                \
      int slot = atomicAdd(&cnt[b], 1);                                       \
      if (slot < CAP)                                                         \
        cb[slot] = ((unsigned long long)u << 32) |                            \
                   (unsigned)(N_ - 1 - (n0 + off));                           \
    }                                                                         \
  }
  DO_CAND(v.x, 0) DO_CAND(v.y, 1) DO_CAND(v.z, 2) DO_CAND(v.w, 3)
#undef DO_CAND
}

// --------------------------- k_final ---------------------------------------
__global__ __launch_bounds__(64) void k_final(const unsigned long long* __restrict__ cand,
                                              const int* __restrict__ cnt,
                                              const float* __restrict__ p2,
                                              const float* __restrict__ g2,
                                              const float* __restrict__ bt2,
                                              const float* __restrict__ inp,
                                              float* __restrict__ out) {
  const int b = blockIdx.x, l = threadIdx.x;

  // stats2 from 256 block partials (fixed-order tree, same in all blocks)
  float s1 = (p2[2 * l] + p2[2 * (l + 64)]) +
             (p2[2 * (l + 128)] + p2[2 * (l + 192)]);
  float q1 = (p2[2 * l + 1] + p2[2 * (l + 64) + 1]) +
             (p2[2 * (l + 128) + 1] + p2[2 * (l + 192) + 1]);
#pragma unroll
  for (int off = 32; off; off >>= 1) {
    s1 += __shfl_down(s1, off, 64);
    q1 += __shfl_down(q1, off, 64);
  }
  s1 = __shfl(s1, 0, 64);
  q1 = __shfl(q1, 0, 64);
  const float inv = 1.f / (float)S_;
  const float mean = s1 * inv;
  const float var  = q1 * inv - mean * mean;
  const float scale2 = g2[0] * rsqrtf(var + EPS_);
  const float shift2 = bt2[0] - mean * scale2;

  int cn = cnt[b];
  if (cn > CAP) cn = CAP;
  const unsigned long long* cb = cand + (long long)b * CAP;
  unsigned long long k[16];
#pragma unroll
  for (int r = 0; r < 16; ++r) {
    int i = l + r * 64;
    k[r] = (i < cn) ? cb[i] : 0ull;
  }
  unsigned long long cur = 0ull;
#pragma unroll
  for (int r = 0; r < 16; ++r) cur = k[r] > cur ? k[r] : cur;

  int myidx = 0;
  unsigned mymap = 0;
  for (int r = 0; r < K_; ++r) {
    unsigned long long m = cur;
#pragma unroll
    for (int off = 32; off; off >>= 1) {
      unsigned long long o = __shfl_xor(m, off, 64);
      m = o > m ? o : m;
    }
    if (r == l) {
      myidx = N_ - 1 - (int)(m & 0xffffffffu);
      mymap = (unsigned)(m >> 32);
    }
    if (cur == m) {          // exactly one lane (keys unique)
#pragma unroll
      for (int r2 = 0; r2 < 16; ++r2)
        if (k[r2] == m) k[r2] = 0ull;
      unsigned long long c2 = 0ull;
#pragma unroll
      for (int r2 = 0; r2 < 16; ++r2) c2 = k[r2] > c2 ? k[r2] : c2;
      cur = c2;
    }
  }

  unsigned u = mymap;
  u = (u & 0x80000000u) ? (u & 0x7fffffffu) : ~u;
  float v = __uint_as_float(u);
  float scv = fmaf(v, scale2, shift2);
  scv = scv > 0.f ? scv : 0.f;

  const float* ib = inp + ((long long)b * 64) * N_;
#pragma unroll 4
  for (int f = 0; f < 64; ++f)
    out[((long long)b * 65 + f) * 64 + l] = ib[(long long)f * N_ + myidx];
  out[((long long)b * 65 + 64) * 64 + l] = scv;
  out[(long long)B_ * 65 * 64 + b * 64 + l] = (float)myidx;
}

// --------------------------- launch ----------------------------------------
extern "C" void kernel_launch(void* const* d_in, const int* in_sizes, int n_in,
                              void* d_out, int out_size, void* d_ws, size_t ws_size,
                              hipStream_t stream) {
  const float* sv  = (const float*)d_in[0];
  const float* inp = (const float*)d_in[1];
  const float* w0  = (const float*)d_in[2];
  const float* b0  = (const float*)d_in[3];
  const float* w1  = (const float*)d_in[4];
  const float* b1  = (const float*)d_in[5];
  const float* w2  = (const float*)d_in[6];
  const float* b2  = (const float*)d_in[7];
  const float* g0  = (const float*)d_in[8];
  const float* bt0 = (const float*)d_in[9];
  const float* g1  = (const float*)d_in[10];
  const float* bt1 = (const float*)d_in[11];
  const float* g2  = (const float*)d_in[12];
  const float* bt2 = (const float*)d_in[13];
  float* out = (float*)d_out;

  float* ws  = (float*)d_ws;
  float* y1  = ws;                                    // S*16     = 8388608
  float* y2  = y1 + (size_t)S_ * 16;                  // S        =  524288
  float* p0  = y2 + (size_t)S_;                       // 2048*128 =  262144
  float* p1  = p0 + (size_t)NB0 * 128;                // 2048*32  =   65536
  float* p2  = p1 + (size_t)NB1 * 32;                 // 256*2    =     512
  float* st0 = p2 + (size_t)NB2 * 2;                  // 128
  float* st1 = st0 + 128;                             // 32
  float* w0T = st1 + 32;                              // 4096
  float* w1T = w0T + 4096;                            // 1024
  int*   ghist = (int*)(w1T + 1024);                  // 16*4096 ints
  int*   cnt   = ghist + (size_t)B_ * NBINS;          // 16 ints
  int*   Tb    = cnt + 16;                            // 16 ints
  unsigned long long* cand =
      (unsigned long long*)(Tb + 16);                 // 16*CAP u64

  hipMemsetAsync(ghist, 0, ((size_t)B_ * NBINS + 16) * sizeof(int), stream);

  k_prep   <<<1,    256, 0, stream>>>(w0, w1, w0T, w1T);
  k_stat0  <<<NB0,  256, 0, stream>>>(sv, w0T, b0, p0);
  k_reduce0<<<1,   1024, 0, stream>>>(p0, g0, bt0, st0);
  k_layer01<<<NB1,  256, 0, stream>>>(sv, w0T, b0, st0, w1T, b1, y1, p1);
  k_reduce1<<<1,   1024, 0, stream>>>(p1, g1, bt1, st1);
  k_layer2 <<<NB2, 1024, 0, stream>>>(y1, st1, w2, b2, y2, p2, ghist);
  k_thresh <<<B_,   256, 0, stream>>>(ghist, Tb);
  k_compact<<<NBC, 1024, 0, stream>>>(y2, Tb, cnt, cand);
  k_final  <<<B_,    64, 0, stream>>>(cand, cnt, p2, g2, bt2, inp, out);
}